// Round 3
// baseline (36.503 us; speedup 1.0000x reference)
//
#include <hip/hip_runtime.h>

#define NJ   24
#define BLK  256
#define EMOF (NJ * 16)   // float offset of the 12-float exp(M) record

// ---------------------------------------------------------------------------
// Prep kernel (1 tiny block): per-joint records, 16 floats each:
//  [0..2]  W = w/sqrt(k)   [3]  sqk = sqrt(k)
//  [4..6]  v               [7]  0
//  [8..10] c1' = (w x v)/k [11] 0
//  [12..14] c2' = (w x (w x v))/k^1.5  [15] 0
// exp(M) (rotation 9 + translation 3) at float offset EMOF.
// ---------------------------------------------------------------------------
__global__ void poe_prep(const float* __restrict__ eta,
                         const float* __restrict__ M,
                         float* __restrict__ cst)
{
    const int t = threadIdx.x;
    if (t < NJ) {
        const float w0 = eta[t*6+0], w1 = eta[t*6+1], w2 = eta[t*6+2];
        const float v0 = eta[t*6+3], v1 = eta[t*6+4], v2 = eta[t*6+5];
        const float k  = w0*w0 + w1*w1 + w2*w2;
        const bool  sm = (k < 1e-12f);
        const float invsqk = sm ? 0.0f : rsqrtf(k);
        const float sqk    = k * invsqk;          // 0 if degenerate
        const float invk   = invsqk * invsqk;
        const float invk15 = invk * invsqk;
        const float c10 = w1*v2 - w2*v1;
        const float c11 = w2*v0 - w0*v2;
        const float c12 = w0*v1 - w1*v0;
        const float c20 = w1*c12 - w2*c11;
        const float c21 = w2*c10 - w0*c12;
        const float c22 = w0*c11 - w1*c10;
        float* r = cst + t * 16;
        r[0]  = w0*invsqk;  r[1]  = w1*invsqk;  r[2]  = w2*invsqk;  r[3]  = sqk;
        r[4]  = v0;         r[5]  = v1;         r[6]  = v2;         r[7]  = 0.0f;
        r[8]  = c10*invk;   r[9]  = c11*invk;   r[10] = c12*invk;   r[11] = 0.0f;
        r[12] = c20*invk15; r[13] = c21*invk15; r[14] = c22*invk15; r[15] = 0.0f;
    } else if (t == NJ) {
        const float w0 = M[0], w1 = M[1], w2 = M[2];
        const float v0 = M[3], v1 = M[4], v2 = M[5];
        const float t2 = w0*w0 + w1*w1 + w2*w2;
        const bool  sm = (t2 < 1e-12f);
        const float t2s  = sm ? 1.0f : t2;
        const float invt = rsqrtf(t2s);
        const float th   = t2s * invt;
        float s, c;
        __sincosf(th, &s, &c);
        const float invt2 = invt * invt;
        const float A = sm ? 1.0f        : s * invt;
        const float B = sm ? 0.5f        : (1.0f - c) * invt2;
        const float C = sm ? (1.0f/6.0f) : (th - s) * invt2 * invt;
        float* r = cst + EMOF;
        r[0] = 1.0f + B*(w0*w0 - t2);
        r[1] = B*w0*w1 - A*w2;
        r[2] = B*w0*w2 + A*w1;
        r[3] = B*w0*w1 + A*w2;
        r[4] = 1.0f + B*(w1*w1 - t2);
        r[5] = B*w1*w2 - A*w0;
        r[6] = B*w0*w2 - A*w1;
        r[7] = B*w1*w2 + A*w0;
        r[8] = 1.0f + B*(w2*w2 - t2);
        const float c10 = w1*v2 - w2*v1, c11 = w2*v0 - w0*v2, c12 = w0*v1 - w1*v0;
        const float c20 = w1*c12 - w2*c11, c21 = w2*c10 - w0*c12, c22 = w0*c11 - w1*c10;
        r[9]  = v0 + B*c10 + C*c20;
        r[10] = v1 + B*c11 + C*c21;
        r[11] = v2 + B*c12 + C*c22;
    }
}

// ---------------------------------------------------------------------------
// Main kernel: 2 threads per batch row. Even thread: joints 0..11, odd:
// 12..23. Each computes its half-product (R,p) over 12 joints with a
// half-length dependency chain, then the pair combines via __shfl_xor and
// both lanes redundantly finish T*exp(M); stores split by parity.
// E_j = I + sin(phi)*skew(W) + (1-cos(phi))*(W W^T - I),
// q_j = a*v + (1-cos(phi))*c1' + (phi-sin(phi))*c2',  phi = a*sqk (signed).
// ---------------------------------------------------------------------------
__global__ __launch_bounds__(BLK)
void poe_main(const float* __restrict__ x,
              const float* __restrict__ cst,
              float* __restrict__ out,
              int nBatch)
{
    const int gid  = blockIdx.x * BLK + threadIdx.x;
    const int row  = gid >> 1;
    const int half = gid & 1;
    const bool active = row < nBatch;

    // ---- own half-row of x: 12 floats = 3 float4 (16B-aligned: 96B rows) ----
    float4 xa = make_float4(0,0,0,0), xb = xa, xc = xa;
    if (active) {
        const float4* xr = (const float4*)(x + (size_t)row * NJ + half * 12);
        xa = xr[0]; xb = xr[1]; xc = xr[2];
    }
    const float av[12] = { xa.x,xa.y,xa.z,xa.w, xb.x,xb.y,xb.z,xb.w,
                           xc.x,xc.y,xc.z,xc.w };

    float R00=1.f,R01=0.f,R02=0.f;
    float R10=0.f,R11=1.f,R12=0.f;
    float R20=0.f,R21=0.f,R22=1.f;
    float p0=0.f,p1=0.f,p2=0.f;

    const float4* jc = (const float4*)cst + (size_t)half * 12 * 4;

    #pragma unroll
    for (int j = 0; j < 12; ++j) {
        const float4 A4 = jc[j*4+0];   // W0 W1 W2 sqk
        const float4 B4 = jc[j*4+1];   // v
        const float4 C4 = jc[j*4+2];   // c1'
        const float4 D4 = jc[j*4+3];   // c2'
        const float a   = av[j];
        const float phi = a * A4.w;
        float s, c;
        __sincosf(phi, &s, &c);
        const float cB = 1.0f - c;
        const float g  = phi - s;

        const float W0 = A4.x, W1 = A4.y, W2 = A4.z;
        const float ww01 = W0*W1, ww02 = W0*W2, ww12 = W1*W2;
        const float d0 = fmaf(W0,W0,-1.0f);
        const float d1 = fmaf(W1,W1,-1.0f);
        const float d2 = fmaf(W2,W2,-1.0f);

        const float e00 = fmaf(cB, d0, 1.0f);
        const float e11 = fmaf(cB, d1, 1.0f);
        const float e22 = fmaf(cB, d2, 1.0f);
        const float t01 = cB * ww01;
        const float t02 = cB * ww02;
        const float t12 = cB * ww12;
        const float e01 = fmaf(-s, W2, t01);
        const float e10 = fmaf( s, W2, t01);
        const float e02 = fmaf( s, W1, t02);
        const float e20 = fmaf(-s, W1, t02);
        const float e12 = fmaf(-s, W0, t12);
        const float e21 = fmaf( s, W0, t12);

        const float q0 = fmaf(a, B4.x, fmaf(cB, C4.x, g * D4.x));
        const float q1 = fmaf(a, B4.y, fmaf(cB, C4.y, g * D4.y));
        const float q2 = fmaf(a, B4.z, fmaf(cB, C4.z, g * D4.z));

        const float n00 = fmaf(R00,e00, fmaf(R01,e10, R02*e20));
        const float n01 = fmaf(R00,e01, fmaf(R01,e11, R02*e21));
        const float n02 = fmaf(R00,e02, fmaf(R01,e12, R02*e22));
        const float n10 = fmaf(R10,e00, fmaf(R11,e10, R12*e20));
        const float n11 = fmaf(R10,e01, fmaf(R11,e11, R12*e21));
        const float n12 = fmaf(R10,e02, fmaf(R11,e12, R12*e22));
        const float n20 = fmaf(R20,e00, fmaf(R21,e10, R22*e20));
        const float n21 = fmaf(R20,e01, fmaf(R21,e11, R22*e21));
        const float n22 = fmaf(R20,e02, fmaf(R21,e12, R22*e22));
        p0 = fmaf(R00,q0, fmaf(R01,q1, fmaf(R02,q2, p0)));
        p1 = fmaf(R10,q0, fmaf(R11,q1, fmaf(R12,q2, p1)));
        p2 = fmaf(R20,q0, fmaf(R21,q1, fmaf(R22,q2, p2)));
        R00=n00; R01=n01; R02=n02;
        R10=n10; R11=n11; R12=n12;
        R20=n20; R21=n21; R22=n22;
    }

    // ---- exchange half-products within the lane pair ----
    const float o00 = __shfl_xor(R00,1), o01 = __shfl_xor(R01,1), o02 = __shfl_xor(R02,1);
    const float o10 = __shfl_xor(R10,1), o11 = __shfl_xor(R11,1), o12 = __shfl_xor(R12,1);
    const float o20 = __shfl_xor(R20,1), o21 = __shfl_xor(R21,1), o22 = __shfl_xor(R22,1);
    const float op0 = __shfl_xor(p0,1),  op1 = __shfl_xor(p1,1),  op2 = __shfl_xor(p2,1);

    const bool h = (half != 0);
    const float a00 = h ? o00 : R00, a01 = h ? o01 : R01, a02 = h ? o02 : R02;
    const float a10 = h ? o10 : R10, a11 = h ? o11 : R11, a12 = h ? o12 : R12;
    const float a20 = h ? o20 : R20, a21 = h ? o21 : R21, a22 = h ? o22 : R22;
    const float ap0 = h ? op0 : p0,  ap1 = h ? op1 : p1,  ap2 = h ? op2 : p2;
    const float b00 = h ? R00 : o00, b01 = h ? R01 : o01, b02 = h ? R02 : o02;
    const float b10 = h ? R10 : o10, b11 = h ? R11 : o11, b12 = h ? R12 : o12;
    const float b20 = h ? R20 : o20, b21 = h ? R21 : o21, b22 = h ? R22 : o22;
    const float bp0 = h ? p0  : op0, bp1 = h ? p1  : op1, bp2 = h ? p2  : op2;

    // ---- T = A * B (both lanes redundantly) ----
    const float c00 = fmaf(a00,b00, fmaf(a01,b10, a02*b20));
    const float c01 = fmaf(a00,b01, fmaf(a01,b11, a02*b21));
    const float c02 = fmaf(a00,b02, fmaf(a01,b12, a02*b22));
    const float c10 = fmaf(a10,b00, fmaf(a11,b10, a12*b20));
    const float c11 = fmaf(a10,b01, fmaf(a11,b11, a12*b21));
    const float c12 = fmaf(a10,b02, fmaf(a11,b12, a12*b22));
    const float c20 = fmaf(a20,b00, fmaf(a21,b10, a22*b20));
    const float c21 = fmaf(a20,b01, fmaf(a21,b11, a22*b21));
    const float c22 = fmaf(a20,b02, fmaf(a21,b12, a22*b22));
    const float cp0 = fmaf(a00,bp0, fmaf(a01,bp1, fmaf(a02,bp2, ap0)));
    const float cp1 = fmaf(a10,bp0, fmaf(a11,bp1, fmaf(a12,bp2, ap1)));
    const float cp2 = fmaf(a20,bp0, fmaf(a21,bp1, fmaf(a22,bp2, ap2)));

    // ---- * exp(M) (uniform address -> scalar loads) ----
    const float* em = cst + EMOF;
    const float m00=em[0], m01=em[1], m02=em[2];
    const float m10=em[3], m11=em[4], m12=em[5];
    const float m20=em[6], m21=em[7], m22=em[8];
    const float mp0=em[9], mp1=em[10], mp2=em[11];

    const float f00 = fmaf(c00,m00, fmaf(c01,m10, c02*m20));
    const float f01 = fmaf(c00,m01, fmaf(c01,m11, c02*m21));
    const float f02 = fmaf(c00,m02, fmaf(c01,m12, c02*m22));
    const float f10 = fmaf(c10,m00, fmaf(c11,m10, c12*m20));
    const float f11 = fmaf(c10,m01, fmaf(c11,m11, c12*m21));
    const float f12 = fmaf(c10,m02, fmaf(c11,m12, c12*m22));
    const float f20 = fmaf(c20,m00, fmaf(c21,m10, c22*m20));
    const float f21 = fmaf(c20,m01, fmaf(c21,m11, c22*m21));
    const float f22 = fmaf(c20,m02, fmaf(c21,m12, c22*m22));
    const float fp0 = fmaf(c00,mp0, fmaf(c01,mp1, fmaf(c02,mp2, cp0)));
    const float fp1 = fmaf(c10,mp0, fmaf(c11,mp1, fmaf(c12,mp2, cp1)));
    const float fp2 = fmaf(c20,mp0, fmaf(c21,mp1, fmaf(c22,mp2, cp2)));

    // ---- store: even lane -> rows 0,1; odd lane -> rows 2,3 ----
    if (active) {
        const float4 lo = h ? make_float4(f20, f21, f22, fp2)
                            : make_float4(f00, f01, f02, fp0);
        const float4 hi = h ? make_float4(0.0f, 0.0f, 0.0f, 1.0f)
                            : make_float4(f10, f11, f12, fp1);
        float4* o = (float4*)(out + (size_t)row * 16) + half * 2;
        o[0] = lo;
        o[1] = hi;
    }
}

extern "C" void kernel_launch(void* const* d_in, const int* in_sizes, int n_in,
                              void* d_out, int out_size, void* d_ws, size_t ws_size,
                              hipStream_t stream)
{
    const float* x   = (const float*)d_in[0];
    const float* eta = (const float*)d_in[1];
    const float* M   = (const float*)d_in[2];
    float* out = (float*)d_out;
    float* cst = (float*)d_ws;

    const int nBatch   = in_sizes[0] / NJ;
    const int nThreads = nBatch * 2;
    const int grid     = (nThreads + BLK - 1) / BLK;

    poe_prep<<<1, 64, 0, stream>>>(eta, M, cst);
    poe_main<<<grid, BLK, 0, stream>>>(x, cst, out, nBatch);
}

// Round 4
// 30.919 us; speedup vs baseline: 1.1806x; 1.1806x over previous
//
#include <hip/hip_runtime.h>

#define NJ   24
#define BLK  256
#define ROWS 2                 // rows (batch elements) per thread
#define EMOF (NJ * 16)         // float offset of the 12-float exp(M) record

// ---------------------------------------------------------------------------
// Prep kernel (1 tiny block): per-joint records, 16 floats each:
//  [0..2]  W = w/sqrt(k)   [3]  sqk = sqrt(k)
//  [4..6]  v               [7]  0
//  [8..10] c1' = (w x v)/k [11] 0
//  [12..14] c2' = (w x (w x v))/k^1.5  [15] 0
// exp(M) (rotation 9 + translation 3) at float offset EMOF.
// ---------------------------------------------------------------------------
__global__ void poe_prep(const float* __restrict__ eta,
                         const float* __restrict__ M,
                         float* __restrict__ cst)
{
    const int t = threadIdx.x;
    if (t < NJ) {
        const float w0 = eta[t*6+0], w1 = eta[t*6+1], w2 = eta[t*6+2];
        const float v0 = eta[t*6+3], v1 = eta[t*6+4], v2 = eta[t*6+5];
        const float k  = w0*w0 + w1*w1 + w2*w2;
        const bool  sm = (k < 1e-12f);
        const float invsqk = sm ? 0.0f : rsqrtf(k);
        const float sqk    = k * invsqk;          // 0 if degenerate
        const float invk   = invsqk * invsqk;
        const float invk15 = invk * invsqk;
        const float c10 = w1*v2 - w2*v1;
        const float c11 = w2*v0 - w0*v2;
        const float c12 = w0*v1 - w1*v0;
        const float c20 = w1*c12 - w2*c11;
        const float c21 = w2*c10 - w0*c12;
        const float c22 = w0*c11 - w1*c10;
        float* r = cst + t * 16;
        r[0]  = w0*invsqk;  r[1]  = w1*invsqk;  r[2]  = w2*invsqk;  r[3]  = sqk;
        r[4]  = v0;         r[5]  = v1;         r[6]  = v2;         r[7]  = 0.0f;
        r[8]  = c10*invk;   r[9]  = c11*invk;   r[10] = c12*invk;   r[11] = 0.0f;
        r[12] = c20*invk15; r[13] = c21*invk15; r[14] = c22*invk15; r[15] = 0.0f;
    } else if (t == NJ) {
        const float w0 = M[0], w1 = M[1], w2 = M[2];
        const float v0 = M[3], v1 = M[4], v2 = M[5];
        const float t2 = w0*w0 + w1*w1 + w2*w2;
        const bool  sm = (t2 < 1e-12f);
        const float t2s  = sm ? 1.0f : t2;
        const float invt = rsqrtf(t2s);
        const float th   = t2s * invt;
        float s, c;
        __sincosf(th, &s, &c);
        const float invt2 = invt * invt;
        const float A = sm ? 1.0f        : s * invt;
        const float B = sm ? 0.5f        : (1.0f - c) * invt2;
        const float C = sm ? (1.0f/6.0f) : (th - s) * invt2 * invt;
        float* r = cst + EMOF;
        r[0] = 1.0f + B*(w0*w0 - t2);
        r[1] = B*w0*w1 - A*w2;
        r[2] = B*w0*w2 + A*w1;
        r[3] = B*w0*w1 + A*w2;
        r[4] = 1.0f + B*(w1*w1 - t2);
        r[5] = B*w1*w2 - A*w0;
        r[6] = B*w0*w2 - A*w1;
        r[7] = B*w1*w2 + A*w0;
        r[8] = 1.0f + B*(w2*w2 - t2);
        const float c10 = w1*v2 - w2*v1, c11 = w2*v0 - w0*v2, c12 = w0*v1 - w1*v0;
        const float c20 = w1*c12 - w2*c11, c21 = w2*c10 - w0*c12, c22 = w0*c11 - w1*c10;
        r[9]  = v0 + B*c10 + C*c20;
        r[10] = v1 + B*c11 + C*c21;
        r[11] = v2 + B*c12 + C*c22;
    }
}

// ---------------------------------------------------------------------------
// One chain's running transform (R, p), bottom row implicit [0 0 0 1].
// ---------------------------------------------------------------------------
struct Chain {
    float R00,R01,R02, R10,R11,R12, R20,R21,R22, p0,p1,p2;
    __device__ void init() {
        R00=1.f;R01=0.f;R02=0.f; R10=0.f;R11=1.f;R12=0.f; R20=0.f;R21=0.f;R22=1.f;
        p0=0.f;p1=0.f;p2=0.f;
    }
    __device__ void step(float a, float4 A4, float4 B4, float4 C4, float4 D4) {
        const float phi = a * A4.w;
        float s, c;
        __sincosf(phi, &s, &c);
        const float cB = 1.0f - c;
        const float g  = phi - s;

        const float W0 = A4.x, W1 = A4.y, W2 = A4.z;
        const float t01 = cB * (W0*W1);
        const float t02 = cB * (W0*W2);
        const float t12 = cB * (W1*W2);
        const float e00 = fmaf(cB, fmaf(W0,W0,-1.0f), 1.0f);
        const float e11 = fmaf(cB, fmaf(W1,W1,-1.0f), 1.0f);
        const float e22 = fmaf(cB, fmaf(W2,W2,-1.0f), 1.0f);
        const float e01 = fmaf(-s, W2, t01);
        const float e10 = fmaf( s, W2, t01);
        const float e02 = fmaf( s, W1, t02);
        const float e20 = fmaf(-s, W1, t02);
        const float e12 = fmaf(-s, W0, t12);
        const float e21 = fmaf( s, W0, t12);

        const float q0 = fmaf(a, B4.x, fmaf(cB, C4.x, g * D4.x));
        const float q1 = fmaf(a, B4.y, fmaf(cB, C4.y, g * D4.y));
        const float q2 = fmaf(a, B4.z, fmaf(cB, C4.z, g * D4.z));

        const float n00 = fmaf(R00,e00, fmaf(R01,e10, R02*e20));
        const float n01 = fmaf(R00,e01, fmaf(R01,e11, R02*e21));
        const float n02 = fmaf(R00,e02, fmaf(R01,e12, R02*e22));
        const float n10 = fmaf(R10,e00, fmaf(R11,e10, R12*e20));
        const float n11 = fmaf(R10,e01, fmaf(R11,e11, R12*e21));
        const float n12 = fmaf(R10,e02, fmaf(R11,e12, R12*e22));
        const float n20 = fmaf(R20,e00, fmaf(R21,e10, R22*e20));
        const float n21 = fmaf(R20,e01, fmaf(R21,e11, R22*e21));
        const float n22 = fmaf(R20,e02, fmaf(R21,e12, R22*e22));
        p0 = fmaf(R00,q0, fmaf(R01,q1, fmaf(R02,q2, p0)));
        p1 = fmaf(R10,q0, fmaf(R11,q1, fmaf(R12,q2, p1)));
        p2 = fmaf(R20,q0, fmaf(R21,q1, fmaf(R22,q2, p2)));
        R00=n00; R01=n01; R02=n02;
        R10=n10; R11=n11; R12=n12;
        R20=n20; R21=n21; R22=n22;
    }
    // out = (this * exp(M)), em = 12 floats (rotation 9, translation 3)
    __device__ void finish_store(const float* em, float* o16) {
        const float m00=em[0], m01=em[1], m02=em[2];
        const float m10=em[3], m11=em[4], m12=em[5];
        const float m20=em[6], m21=em[7], m22=em[8];
        const float mp0=em[9], mp1=em[10], mp2=em[11];
        const float f00 = fmaf(R00,m00, fmaf(R01,m10, R02*m20));
        const float f01 = fmaf(R00,m01, fmaf(R01,m11, R02*m21));
        const float f02 = fmaf(R00,m02, fmaf(R01,m12, R02*m22));
        const float f10 = fmaf(R10,m00, fmaf(R11,m10, R12*m20));
        const float f11 = fmaf(R10,m01, fmaf(R11,m11, R12*m21));
        const float f12 = fmaf(R10,m02, fmaf(R11,m12, R12*m22));
        const float f20 = fmaf(R20,m00, fmaf(R21,m10, R22*m20));
        const float f21 = fmaf(R20,m01, fmaf(R21,m11, R22*m21));
        const float f22 = fmaf(R20,m02, fmaf(R21,m12, R22*m22));
        const float fp0 = fmaf(R00,mp0, fmaf(R01,mp1, fmaf(R02,mp2, p0)));
        const float fp1 = fmaf(R10,mp0, fmaf(R11,mp1, fmaf(R12,mp2, p1)));
        const float fp2 = fmaf(R20,mp0, fmaf(R21,mp1, fmaf(R22,mp2, p2)));
        float4* o = (float4*)o16;
        o[0] = make_float4(f00, f01, f02, fp0);
        o[1] = make_float4(f10, f11, f12, fp1);
        o[2] = make_float4(f20, f21, f22, fp2);
        o[3] = make_float4(0.0f, 0.0f, 0.0f, 1.0f);
    }
};

// ---------------------------------------------------------------------------
// Main kernel: each thread carries ROWS=2 independent chains (rows r0, r1 =
// r0+BLK). Constants live in LDS (staged once, broadcast ds_read_b128 --
// in-order completion lets the compiler pipeline with partial lgkmcnt).
// x is loaded directly as float4 (rows are 96B, 16B-aligned).
// ---------------------------------------------------------------------------
__global__ __launch_bounds__(BLK)
void poe_main(const float* __restrict__ x,
              const float* __restrict__ cst,
              float* __restrict__ out,
              int nBatch)
{
    __shared__ float4 sC[NJ * 4];

    if (threadIdx.x < NJ * 4) {
        sC[threadIdx.x] = ((const float4*)cst)[threadIdx.x];
    }
    __syncthreads();

    const int r0 = blockIdx.x * (BLK * ROWS) + threadIdx.x;
    const int r1 = r0 + BLK;
    const bool a0 = r0 < nBatch;
    const bool a1 = r1 < nBatch;

    // ---- load both rows of x (6 float4 each, hoisted) ----
    float4 xz = make_float4(0,0,0,0);
    float4 xA0=xz,xA1=xz,xA2=xz,xA3=xz,xA4=xz,xA5=xz;
    float4 xB0=xz,xB1=xz,xB2=xz,xB3=xz,xB4=xz,xB5=xz;
    if (a0) {
        const float4* xr = (const float4*)(x + (size_t)r0 * NJ);
        xA0=xr[0]; xA1=xr[1]; xA2=xr[2]; xA3=xr[3]; xA4=xr[4]; xA5=xr[5];
    }
    if (a1) {
        const float4* xr = (const float4*)(x + (size_t)r1 * NJ);
        xB0=xr[0]; xB1=xr[1]; xB2=xr[2]; xB3=xr[3]; xB4=xr[4]; xB5=xr[5];
    }
    const float avA[NJ] = { xA0.x,xA0.y,xA0.z,xA0.w, xA1.x,xA1.y,xA1.z,xA1.w,
                            xA2.x,xA2.y,xA2.z,xA2.w, xA3.x,xA3.y,xA3.z,xA3.w,
                            xA4.x,xA4.y,xA4.z,xA4.w, xA5.x,xA5.y,xA5.z,xA5.w };
    const float avB[NJ] = { xB0.x,xB0.y,xB0.z,xB0.w, xB1.x,xB1.y,xB1.z,xB1.w,
                            xB2.x,xB2.y,xB2.z,xB2.w, xB3.x,xB3.y,xB3.z,xB3.w,
                            xB4.x,xB4.y,xB4.z,xB4.w, xB5.x,xB5.y,xB5.z,xB5.w };

    Chain TA, TB;
    TA.init();
    TB.init();

    #pragma unroll 4
    for (int j = 0; j < NJ; ++j) {
        const float4 A4 = sC[j*4+0];
        const float4 B4 = sC[j*4+1];
        const float4 C4 = sC[j*4+2];
        const float4 D4 = sC[j*4+3];
        TA.step(avA[j], A4, B4, C4, D4);
        TB.step(avB[j], A4, B4, C4, D4);
    }

    const float* em = cst + EMOF;   // uniform -> scalar loads, one-time drain
    if (a0) TA.finish_store(em, out + (size_t)r0 * 16);
    if (a1) TB.finish_store(em, out + (size_t)r1 * 16);
}

extern "C" void kernel_launch(void* const* d_in, const int* in_sizes, int n_in,
                              void* d_out, int out_size, void* d_ws, size_t ws_size,
                              hipStream_t stream)
{
    const float* x   = (const float*)d_in[0];
    const float* eta = (const float*)d_in[1];
    const float* M   = (const float*)d_in[2];
    float* out = (float*)d_out;
    float* cst = (float*)d_ws;

    const int nBatch      = in_sizes[0] / NJ;
    const int rowsPerBlk  = BLK * ROWS;
    const int grid        = (nBatch + rowsPerBlk - 1) / rowsPerBlk;

    poe_prep<<<1, 64, 0, stream>>>(eta, M, cst);
    poe_main<<<grid, BLK, 0, stream>>>(x, cst, out, nBatch);
}

// Round 5
// 27.119 us; speedup vs baseline: 1.3460x; 1.1401x over previous
//
#include <hip/hip_runtime.h>

#define NJ   24
#define BLK  256
#define ROWS 2                 // rows (batch elements) per thread
#define EMOF (NJ * 16)         // float offset of the 12-float exp(M) record
#define INV2PI 0.15915494309189535f

// ---------------------------------------------------------------------------
// Prep kernel (1 tiny block): per-joint records, 16 floats each:
//  [0..2]  W = w/sqrt(k)     [3]  sqk = sqrt(k)
//  [4..6]  v                 [7]  sqk/(2*pi)   (for hw v_sin/v_cos, revolutions)
//  [8..10] c1' = (w x v)/k   [11] 0
//  [12..14] c2' = (w x (w x v))/k^1.5  [15] 0
// exp(M) (rotation 9 + translation 3) at float offset EMOF.
// ---------------------------------------------------------------------------
__global__ void poe_prep(const float* __restrict__ eta,
                         const float* __restrict__ M,
                         float* __restrict__ cst)
{
    const int t = threadIdx.x;
    if (t < NJ) {
        const float w0 = eta[t*6+0], w1 = eta[t*6+1], w2 = eta[t*6+2];
        const float v0 = eta[t*6+3], v1 = eta[t*6+4], v2 = eta[t*6+5];
        const float k  = w0*w0 + w1*w1 + w2*w2;
        const bool  sm = (k < 1e-12f);
        const float invsqk = sm ? 0.0f : rsqrtf(k);
        const float sqk    = k * invsqk;          // 0 if degenerate
        const float invk   = invsqk * invsqk;
        const float invk15 = invk * invsqk;
        const float c10 = w1*v2 - w2*v1;
        const float c11 = w2*v0 - w0*v2;
        const float c12 = w0*v1 - w1*v0;
        const float c20 = w1*c12 - w2*c11;
        const float c21 = w2*c10 - w0*c12;
        const float c22 = w0*c11 - w1*c10;
        float* r = cst + t * 16;
        r[0]  = w0*invsqk;  r[1]  = w1*invsqk;  r[2]  = w2*invsqk;  r[3]  = sqk;
        r[4]  = v0;         r[5]  = v1;         r[6]  = v2;         r[7]  = sqk * INV2PI;
        r[8]  = c10*invk;   r[9]  = c11*invk;   r[10] = c12*invk;   r[11] = 0.0f;
        r[12] = c20*invk15; r[13] = c21*invk15; r[14] = c22*invk15; r[15] = 0.0f;
    } else if (t == NJ) {
        const float w0 = M[0], w1 = M[1], w2 = M[2];
        const float v0 = M[3], v1 = M[4], v2 = M[5];
        const float t2 = w0*w0 + w1*w1 + w2*w2;
        const bool  sm = (t2 < 1e-12f);
        const float t2s  = sm ? 1.0f : t2;
        const float invt = rsqrtf(t2s);
        const float th   = t2s * invt;
        float s, c;
        __sincosf(th, &s, &c);
        const float invt2 = invt * invt;
        const float A = sm ? 1.0f        : s * invt;
        const float B = sm ? 0.5f        : (1.0f - c) * invt2;
        const float C = sm ? (1.0f/6.0f) : (th - s) * invt2 * invt;
        float* r = cst + EMOF;
        r[0] = 1.0f + B*(w0*w0 - t2);
        r[1] = B*w0*w1 - A*w2;
        r[2] = B*w0*w2 + A*w1;
        r[3] = B*w0*w1 + A*w2;
        r[4] = 1.0f + B*(w1*w1 - t2);
        r[5] = B*w1*w2 - A*w0;
        r[6] = B*w0*w2 - A*w1;
        r[7] = B*w1*w2 + A*w0;
        r[8] = 1.0f + B*(w2*w2 - t2);
        const float c10 = w1*v2 - w2*v1, c11 = w2*v0 - w0*v2, c12 = w0*v1 - w1*v0;
        const float c20 = w1*c12 - w2*c11, c21 = w2*c10 - w0*c12, c22 = w0*c11 - w1*c10;
        r[9]  = v0 + B*c10 + C*c20;
        r[10] = v1 + B*c11 + C*c21;
        r[11] = v2 + B*c12 + C*c22;
    }
}

// ---------------------------------------------------------------------------
// Per-joint geometry shared by both chains in a thread.
// ---------------------------------------------------------------------------
struct Geom {
    float W0,W1,W2, sqk, sqkr;
    float ww01,ww02,ww12, d0,d1,d2;
    float4 B4, C4, D4;   // v(+sqkr in w), c1', c2'
    __device__ void load(const float4* sC, int j) {
        const float4 A4 = sC[j*4+0];
        B4 = sC[j*4+1];
        C4 = sC[j*4+2];
        D4 = sC[j*4+3];
        W0 = A4.x; W1 = A4.y; W2 = A4.z; sqk = A4.w; sqkr = B4.w;
        ww01 = W0*W1; ww02 = W0*W2; ww12 = W1*W2;
        d0 = fmaf(W0,W0,-1.0f);
        d1 = fmaf(W1,W1,-1.0f);
        d2 = fmaf(W2,W2,-1.0f);
    }
};

// ---------------------------------------------------------------------------
// One chain's running transform (R, p), bottom row implicit [0 0 0 1].
// ---------------------------------------------------------------------------
struct Chain {
    float R00,R01,R02, R10,R11,R12, R20,R21,R22, p0,p1,p2;
    __device__ void init() {
        R00=1.f;R01=0.f;R02=0.f; R10=0.f;R11=1.f;R12=0.f; R20=0.f;R21=0.f;R22=1.f;
        p0=0.f;p1=0.f;p2=0.f;
    }
    __device__ void step(float a, const Geom& G) {
        const float phi = a * G.sqk;
        const float rev = a * G.sqkr;                  // phi / (2*pi)
        const float s   = __builtin_amdgcn_sinf(rev);  // v_sin_f32 (revolutions)
        const float c   = __builtin_amdgcn_cosf(rev);  // v_cos_f32
        const float cB  = 1.0f - c;
        const float g   = phi - s;

        const float t01 = cB * G.ww01;
        const float t02 = cB * G.ww02;
        const float t12 = cB * G.ww12;
        const float e00 = fmaf(cB, G.d0, 1.0f);
        const float e11 = fmaf(cB, G.d1, 1.0f);
        const float e22 = fmaf(cB, G.d2, 1.0f);
        const float e01 = fmaf(-s, G.W2, t01);
        const float e10 = fmaf( s, G.W2, t01);
        const float e02 = fmaf( s, G.W1, t02);
        const float e20 = fmaf(-s, G.W1, t02);
        const float e12 = fmaf(-s, G.W0, t12);
        const float e21 = fmaf( s, G.W0, t12);

        const float q0 = fmaf(a, G.B4.x, fmaf(cB, G.C4.x, g * G.D4.x));
        const float q1 = fmaf(a, G.B4.y, fmaf(cB, G.C4.y, g * G.D4.y));
        const float q2 = fmaf(a, G.B4.z, fmaf(cB, G.C4.z, g * G.D4.z));

        const float n00 = fmaf(R00,e00, fmaf(R01,e10, R02*e20));
        const float n01 = fmaf(R00,e01, fmaf(R01,e11, R02*e21));
        const float n02 = fmaf(R00,e02, fmaf(R01,e12, R02*e22));
        const float n10 = fmaf(R10,e00, fmaf(R11,e10, R12*e20));
        const float n11 = fmaf(R10,e01, fmaf(R11,e11, R12*e21));
        const float n12 = fmaf(R10,e02, fmaf(R11,e12, R12*e22));
        const float n20 = fmaf(R20,e00, fmaf(R21,e10, R22*e20));
        const float n21 = fmaf(R20,e01, fmaf(R21,e11, R22*e21));
        const float n22 = fmaf(R20,e02, fmaf(R21,e12, R22*e22));
        p0 = fmaf(R00,q0, fmaf(R01,q1, fmaf(R02,q2, p0)));
        p1 = fmaf(R10,q0, fmaf(R11,q1, fmaf(R12,q2, p1)));
        p2 = fmaf(R20,q0, fmaf(R21,q1, fmaf(R22,q2, p2)));
        R00=n00; R01=n01; R02=n02;
        R10=n10; R11=n11; R12=n12;
        R20=n20; R21=n21; R22=n22;
    }
    __device__ void finish_store(const float* em, float* o16) {
        const float m00=em[0], m01=em[1], m02=em[2];
        const float m10=em[3], m11=em[4], m12=em[5];
        const float m20=em[6], m21=em[7], m22=em[8];
        const float mp0=em[9], mp1=em[10], mp2=em[11];
        const float f00 = fmaf(R00,m00, fmaf(R01,m10, R02*m20));
        const float f01 = fmaf(R00,m01, fmaf(R01,m11, R02*m21));
        const float f02 = fmaf(R00,m02, fmaf(R01,m12, R02*m22));
        const float f10 = fmaf(R10,m00, fmaf(R11,m10, R12*m20));
        const float f11 = fmaf(R10,m01, fmaf(R11,m11, R12*m21));
        const float f12 = fmaf(R10,m02, fmaf(R11,m12, R12*m22));
        const float f20 = fmaf(R20,m00, fmaf(R21,m10, R22*m20));
        const float f21 = fmaf(R20,m01, fmaf(R21,m11, R22*m21));
        const float f22 = fmaf(R20,m02, fmaf(R21,m12, R22*m22));
        const float fp0 = fmaf(R00,mp0, fmaf(R01,mp1, fmaf(R02,mp2, p0)));
        const float fp1 = fmaf(R10,mp0, fmaf(R11,mp1, fmaf(R12,mp2, p1)));
        const float fp2 = fmaf(R20,mp0, fmaf(R21,mp1, fmaf(R22,mp2, p2)));
        float4* o = (float4*)o16;
        o[0] = make_float4(f00, f01, f02, fp0);
        o[1] = make_float4(f10, f11, f12, fp1);
        o[2] = make_float4(f20, f21, f22, fp2);
        o[3] = make_float4(0.0f, 0.0f, 0.0f, 1.0f);
    }
};

// ---------------------------------------------------------------------------
// Main kernel: each thread carries ROWS=2 independent chains (rows r0, r1 =
// r0+BLK). Constants in LDS (broadcast ds_read_b128). x loaded directly as
// float4. sin/cos via hardware v_sin_f32/v_cos_f32 (argument in revolutions).
// ---------------------------------------------------------------------------
__global__ __launch_bounds__(BLK)
void poe_main(const float* __restrict__ x,
              const float* __restrict__ cst,
              float* __restrict__ out,
              int nBatch)
{
    __shared__ float4 sC[NJ * 4];

    if (threadIdx.x < NJ * 4) {
        sC[threadIdx.x] = ((const float4*)cst)[threadIdx.x];
    }
    __syncthreads();

    const int r0 = blockIdx.x * (BLK * ROWS) + threadIdx.x;
    const int r1 = r0 + BLK;
    const bool a0 = r0 < nBatch;
    const bool a1 = r1 < nBatch;

    float4 xz = make_float4(0,0,0,0);
    float4 xA0=xz,xA1=xz,xA2=xz,xA3=xz,xA4=xz,xA5=xz;
    float4 xB0=xz,xB1=xz,xB2=xz,xB3=xz,xB4=xz,xB5=xz;
    if (a0) {
        const float4* xr = (const float4*)(x + (size_t)r0 * NJ);
        xA0=xr[0]; xA1=xr[1]; xA2=xr[2]; xA3=xr[3]; xA4=xr[4]; xA5=xr[5];
    }
    if (a1) {
        const float4* xr = (const float4*)(x + (size_t)r1 * NJ);
        xB0=xr[0]; xB1=xr[1]; xB2=xr[2]; xB3=xr[3]; xB4=xr[4]; xB5=xr[5];
    }
    const float avA[NJ] = { xA0.x,xA0.y,xA0.z,xA0.w, xA1.x,xA1.y,xA1.z,xA1.w,
                            xA2.x,xA2.y,xA2.z,xA2.w, xA3.x,xA3.y,xA3.z,xA3.w,
                            xA4.x,xA4.y,xA4.z,xA4.w, xA5.x,xA5.y,xA5.z,xA5.w };
    const float avB[NJ] = { xB0.x,xB0.y,xB0.z,xB0.w, xB1.x,xB1.y,xB1.z,xB1.w,
                            xB2.x,xB2.y,xB2.z,xB2.w, xB3.x,xB3.y,xB3.z,xB3.w,
                            xB4.x,xB4.y,xB4.z,xB4.w, xB5.x,xB5.y,xB5.z,xB5.w };

    Chain TA, TB;
    TA.init();
    TB.init();

    #pragma unroll 4
    for (int j = 0; j < NJ; ++j) {
        Geom G;
        G.load(sC, j);
        TA.step(avA[j], G);
        TB.step(avB[j], G);
    }

    const float* em = cst + EMOF;   // uniform -> scalar loads, one-time drain
    if (a0) TA.finish_store(em, out + (size_t)r0 * 16);
    if (a1) TB.finish_store(em, out + (size_t)r1 * 16);
}

extern "C" void kernel_launch(void* const* d_in, const int* in_sizes, int n_in,
                              void* d_out, int out_size, void* d_ws, size_t ws_size,
                              hipStream_t stream)
{
    const float* x   = (const float*)d_in[0];
    const float* eta = (const float*)d_in[1];
    const float* M   = (const float*)d_in[2];
    float* out = (float*)d_out;
    float* cst = (float*)d_ws;

    const int nBatch      = in_sizes[0] / NJ;
    const int rowsPerBlk  = BLK * ROWS;
    const int grid        = (nBatch + rowsPerBlk - 1) / rowsPerBlk;

    poe_prep<<<1, 64, 0, stream>>>(eta, M, cst);
    poe_main<<<grid, BLK, 0, stream>>>(x, cst, out, nBatch);
}